// Round 3
// baseline (109.536 us; speedup 1.0000x reference)
//
#include <hip/hip_runtime.h>
#include <stdint.h>

#define NTYPES 12
#define EMB 128
#define KNN 30
#define SEPS_F 1e-6f
#define LEPS_F 1e6f
#define NATOMS 4800
#define ITEMS 76            // 75 real + 1 pad per lane
#define GROUPS 19           // ITEMS / 4
#define PADN 4864           // GROUPS * 256 floats per SoA array per batch
#define CAPC 192            // candidate capacity per wave
#define SENT_BITS 0x7F7FFFFFu   // FLT_MAX bits: sentinel for masked items

typedef unsigned long long ull;

__device__ __forceinline__ ull shfl_xor64(ull v, int m) {
    int lo = (int)(unsigned)(v & 0xffffffffull);
    int hi = (int)(unsigned)(v >> 32);
    lo = __shfl_xor(lo, m, 64);
    hi = __shfl_xor(hi, m, 64);
    return ((ull)(unsigned)hi << 32) | (unsigned)lo;
}

// ---------------- prep: mask counts + graph-norm affine coeffs, fused ----------------
__global__ __launch_bounds__(256) void prep_kernel(const float* __restrict__ mask,
                                                   const float* __restrict__ w,
                                                   const float* __restrict__ scale,
                                                   const float* __restrict__ shift,
                                                   float* __restrict__ cnt_all,
                                                   float* __restrict__ Aa,
                                                   float* __restrict__ Bb, int N) {
    __shared__ float lc[NTYPES];
    __shared__ float ltot;
    const int b = blockIdx.x;
    const int t = threadIdx.x;
    if (t < NTYPES) lc[t] = 0.f;
    if (t == 0) ltot = 0.f;
    __syncthreads();

    // n = t + 256*i ; n%12 = (t + 4*(i%3)) % 12  -> only 3 types per thread
    float s0 = 0.f, s1 = 0.f, s2 = 0.f, tot = 0.f;
    const float* mb = mask + (size_t)b * N;
#pragma unroll
    for (int base = 0; base < 21; base += 3) {
        int n0 = t + 256 * base;
        if (n0 < N) { float m = mb[n0]; s0 += m; tot += m; }
        int n1 = t + 256 * (base + 1);
        if (n1 < N) { float m = mb[n1]; s1 += m; tot += m; }
        int n2 = t + 256 * (base + 2);
        if (n2 < N) { float m = mb[n2]; s2 += m; tot += m; }
    }
    atomicAdd(&lc[t % NTYPES], s0);
    atomicAdd(&lc[(t + 4) % NTYPES], s1);
    atomicAdd(&lc[(t + 8) % NTYPES], s2);
    for (int s = 32; s >= 1; s >>= 1) tot += __shfl_xor(tot, s, 64);
    if ((t & 63) == 0) atomicAdd(&ltot, tot);
    __syncthreads();

    if (t < EMB) {
        const int d = t;
        float cnt = ltot;
        float c = (cnt == 0.f) ? 1.f : cnt;
        float mean = 0.f;
#pragma unroll
        for (int tt = 0; tt < NTYPES; ++tt) mean += w[tt * EMB + d] * lc[tt];
        mean /= c;
        float S = 0.f;
#pragma unroll
        for (int tt = 0; tt < NTYPES; ++tt) {
            float dv = w[tt * EMB + d] - mean;
            S += lc[tt] * dv * dv;
        }
        S += ((float)N - cnt) * mean * mean;
        float stdv = sqrtf(S / c + SEPS_F);
        float g = scale[d] / stdv;
        Aa[b * EMB + d] = g;
        Bb[b * EMB + d] = shift[d] - mean * g;
    }
    if (t == 0) cnt_all[b] = ltot;
}

// ---------------- SoA transpose: group-interleaved layout for x4 loads ----------------
// item t of lane l <-> atom j = t*64 + l ; slot = (t/4)*256 + l*4 + (t%4)
__global__ __launch_bounds__(256) void soa_kernel(const float* __restrict__ coords,
                                                  float* __restrict__ soa, int N) {
    const int b = blockIdx.y;
    const int j = blockIdx.x * 256 + threadIdx.x;   // 0..PADN-1
    float x, y, z;
    int slot;
    if (j < N) {
        int t = j >> 6, l = j & 63;
        slot = (t >> 2) * 256 + l * 4 + (t & 3);
        const float* cp = coords + ((size_t)b * N + j) * 3;
        x = cp[0]; y = cp[1]; z = cp[2];
    } else {
        int l = j - N;                              // pad item t = ITEMS-1
        slot = (GROUPS - 1) * 256 + l * 4 + 3;
        x = y = z = 1.0e30f;                        // d2 overflows to +inf
    }
    float* base = soa + (size_t)b * 3 * PADN;
    base[0 * PADN + slot] = x;
    base[1 * PADN + slot] = y;
    base[2 * PADN + slot] = z;
}

// ---------------- embedding write (float4) ----------------
__global__ __launch_bounds__(256) void emb_kernel(const float* __restrict__ w,
                                                  const float* __restrict__ mask,
                                                  const float* __restrict__ Aa,
                                                  const float* __restrict__ Bb,
                                                  float* __restrict__ out0, int N) {
    const int b = blockIdx.y;
    const int idx = blockIdx.x * 256 + threadIdx.x;   // [0, N*EMB/4)
    const int d4 = idx & 31;
    const int n = idx >> 5;
    float m = mask[b * N + n];
    const float4 wv = *(const float4*)(w + (n % NTYPES) * EMB + d4 * 4);
    const float4 av = *(const float4*)(Aa + b * EMB + d4 * 4);
    const float4 bv = *(const float4*)(Bb + b * EMB + d4 * 4);
    float4 o;
    o.x = (wv.x * m * av.x + bv.x) * m;
    o.y = (wv.y * m * av.y + bv.y) * m;
    o.z = (wv.z * m * av.z + bv.z) * m;
    o.w = (wv.w * m * av.w + bv.w) * m;
    *(float4*)(out0 + (size_t)b * N * EMB + (size_t)idx * 4) = o;
}

// ---------------- exact 30-NN: one wave per query row ----------------
__global__ __launch_bounds__(256, 4) void knn_kernel(const float* __restrict__ coords,
                                                     const float* __restrict__ soa,
                                                     const float* __restrict__ mask,
                                                     const float* __restrict__ cnt_all,
                                                     float* __restrict__ outd,
                                                     float* __restrict__ outi,
                                                     int B, int N) {
    __shared__ ull cand[4][CAPC];
    const int wave = threadIdx.x >> 6;
    const int lane = threadIdx.x & 63;
    int row = blockIdx.x * 4 + wave;
    const int total = B * N;
    if (row >= total) row = total - 1;
    const int b = row / N;
    const int i = row - b * N;

    const float* mb = mask + (size_t)b * N;
    const float* cp = coords + ((size_t)b * N + i) * 3;
    const float qx = cp[0], qy = cp[1], qz = cp[2];
    const float mi = mb[i];

    if (mi == 0.f) {
        if (lane < KNN) {
            size_t o0 = (size_t)row * KNN + lane;
            outd[o0] = LEPS_F;
            outi[o0] = -1.f;
        }
        return;
    }

    const bool allOnes = (cnt_all[b] == (float)N);
    const float* xs = soa + (size_t)b * 3 * PADN;
    const float* ys = xs + PADN;
    const float* zs = ys + PADN;
    const int loff = lane << 2;

    unsigned bits[ITEMS];
    unsigned lm = 0xFFFFFFFFu;
    if (allOnes) {
#pragma unroll
        for (int g = 0; g < GROUPS; ++g) {
            const float4 xv = *(const float4*)(xs + g * 256 + loff);
            const float4 yv = *(const float4*)(ys + g * 256 + loff);
            const float4 zv = *(const float4*)(zs + g * 256 + loff);
#pragma unroll
            for (int r = 0; r < 4; ++r) {
                float x = (r == 0) ? xv.x : (r == 1) ? xv.y : (r == 2) ? xv.z : xv.w;
                float y = (r == 0) ? yv.x : (r == 1) ? yv.y : (r == 2) ? yv.z : yv.w;
                float z = (r == 0) ? zv.x : (r == 1) ? zv.y : (r == 2) ? zv.z : zv.w;
                float dx = __fsub_rn(x, qx), dy = __fsub_rn(y, qy), dz = __fsub_rn(z, qz);
                float d2 = __fadd_rn(__fadd_rn(__fmul_rn(dx, dx), __fmul_rn(dy, dy)),
                                     __fmul_rn(dz, dz));
                unsigned ub = __float_as_uint(d2);   // pad item -> +inf bits, never selected
                bits[4 * g + r] = ub;
                lm = (ub < lm) ? ub : lm;
            }
        }
    } else {
#pragma unroll
        for (int g = 0; g < GROUPS; ++g) {
            const float4 xv = *(const float4*)(xs + g * 256 + loff);
            const float4 yv = *(const float4*)(ys + g * 256 + loff);
            const float4 zv = *(const float4*)(zs + g * 256 + loff);
#pragma unroll
            for (int r = 0; r < 4; ++r) {
                int t = 4 * g + r;
                unsigned ub;
                if (t == ITEMS - 1) {
                    ub = 0xFFFFFFFFu;               // pad: no mask load (OOB)
                } else {
                    float x = (r == 0) ? xv.x : (r == 1) ? xv.y : (r == 2) ? xv.z : xv.w;
                    float y = (r == 0) ? yv.x : (r == 1) ? yv.y : (r == 2) ? yv.z : yv.w;
                    float z = (r == 0) ? zv.x : (r == 1) ? zv.y : (r == 2) ? zv.z : zv.w;
                    float dx = __fsub_rn(x, qx), dy = __fsub_rn(y, qy), dz = __fsub_rn(z, qz);
                    float d2 = __fadd_rn(__fadd_rn(__fmul_rn(dx, dx), __fmul_rn(dy, dy)),
                                         __fmul_rn(dz, dz));
                    ub = __float_as_uint(d2);
                    if (mb[t * 64 + lane] == 0.f) ub = SENT_BITS;
                }
                bits[t] = ub;
                lm = (ub < lm) ? ub : lm;
            }
        }
    }

    // ---- threshold estimate: ~35th smallest of the 64 lane-mins ----
    unsigned mx = lm;
    for (int s = 32; s >= 1; s >>= 1) {
        unsigned o = (unsigned)__shfl_xor((int)mx, s, 64);
        mx = (o > mx) ? o : mx;
    }
    unsigned elo = 0, ehi = mx;
    while (elo + 4096u < ehi) {
        unsigned mid = elo + ((ehi - elo) >> 1);
        int cnt = __popcll(__ballot(lm <= mid));
        if (cnt >= 35) ehi = mid; else elo = mid + 1;
    }
    unsigned T = ehi;

    // ---- fused count + compact (ascending atom index), window-adjusted ----
    ull* cw = cand[wave];
    const ull lmaskLT = (1ull << lane) - 1ull;
    int c;
    unsigned blo = 0, bhi = SENT_BITS;
    bool forced = false;
    for (;;) {
        c = 0;
#pragma unroll
        for (int k = 0; k < ITEMS; ++k) {
            bool p = (bits[k] <= T);
            ull bal = __ballot(p);
            if (p) {
                int pos = c + __popcll(bal & lmaskLT);
                if (pos < CAPC)
                    cw[pos] = ((ull)bits[k] << 32) | (unsigned)(k * 64 + lane);
            }
            c += __popcll(bal);
        }
        if (forced || (c >= KNN + 1 && c <= CAPC)) break;
        if (c < KNN + 1) blo = T + 1; else bhi = T - 1;
        if (blo > bhi) { T = blo; forced = true; }
        else T = blo + ((bhi - blo) >> 1);
    }
    if (c > CAPC) c = CAPC;

    asm volatile("s_waitcnt lgkmcnt(0)" ::: "memory");

    if (c <= 64) {
        ull key = ~0ull;
        if (lane < c) {
            ull kk = cw[lane];
            unsigned db = (unsigned)(kk >> 32);
            unsigned jj = (unsigned)kk;
            float dist;
            if (db == SENT_BITS || jj == (unsigned)i) dist = LEPS_F;
            else dist = __fsqrt_rn(__fadd_rn(__uint_as_float(db), SEPS_F));
            key = ((ull)__float_as_uint(dist) << 32) | jj;
        }
        for (int kk2 = 2; kk2 <= 64; kk2 <<= 1) {
            for (int jj2 = kk2 >> 1; jj2 > 0; jj2 >>= 1) {
                ull o = shfl_xor64(key, jj2);
                bool up = ((lane & kk2) == 0);
                bool takeMin = (((lane & jj2) == 0) == up);
                ull mn2 = (key < o) ? key : o;
                ull mx2 = (key < o) ? o : key;
                key = takeMin ? mn2 : mx2;
            }
        }
        if (lane < KNN) {
            unsigned db = (unsigned)(key >> 32);
            unsigned jj = (unsigned)key;
            float dv = __uint_as_float(db);
            float iv = (jj == (unsigned)i) ? -1.f : (float)jj;
            size_t o0 = (size_t)row * KNN + lane;
            outd[o0] = dv;
            outi[o0] = iv;
        }
    } else {
        for (int ci = lane; ci < c; ci += 64) {
            ull kk = cw[ci];
            unsigned db = (unsigned)(kk >> 32);
            unsigned jj = (unsigned)kk;
            float dist;
            if (db == SENT_BITS || jj == (unsigned)i) dist = LEPS_F;
            else dist = __fsqrt_rn(__fadd_rn(__uint_as_float(db), SEPS_F));
            cw[ci] = ((ull)__float_as_uint(dist) << 32) | jj;
        }
        asm volatile("s_waitcnt lgkmcnt(0)" ::: "memory");
        for (int ci = lane; ci < c; ci += 64) {
            ull key = cw[ci];
            int rank = 0;
            for (int o = 0; o < c; ++o) rank += (cw[o] < key) ? 1 : 0;
            if (rank < KNN) {
                unsigned db = (unsigned)(key >> 32);
                unsigned jj = (unsigned)key;
                float dv = __uint_as_float(db);
                float iv = (jj == (unsigned)i) ? -1.f : (float)jj;
                size_t o0 = (size_t)row * KNN + rank;
                outd[o0] = dv;
                outi[o0] = iv;
            }
        }
    }
}

extern "C" void kernel_launch(void* const* d_in, const int* in_sizes, int n_in,
                              void* d_out, int out_size, void* d_ws, size_t ws_size,
                              hipStream_t stream) {
    const float* coords = (const float*)d_in[0];
    const float* mask   = (const float*)d_in[1];
    const float* w      = (const float*)d_in[2];
    const float* scale  = (const float*)d_in[3];
    const float* shift  = (const float*)d_in[4];

    int BN = in_sizes[1];          // B*N
    int N  = NATOMS;
    int B  = BN / N;

    float* ws0     = (float*)d_ws;
    float* cnt_all = ws0;                     // B (padded to 16)
    float* Aa      = ws0 + 16;                // B*128
    float* Bb      = Aa + B * EMB;            // B*128
    float* soa     = Bb + B * EMB;            // B*3*PADN

    float* out0 = (float*)d_out;                      // B*N*128
    float* outd = out0 + (size_t)B * N * EMB;         // B*N*30
    float* outi = outd + (size_t)B * N * KNN;         // B*N*30 (indices as float)

    prep_kernel<<<B, 256, 0, stream>>>(mask, w, scale, shift, cnt_all, Aa, Bb, N);
    soa_kernel<<<dim3(PADN / 256, B), 256, 0, stream>>>(coords, soa, N);
    emb_kernel<<<dim3(N * EMB / 4 / 256, B), 256, 0, stream>>>(w, mask, Aa, Bb, out0, N);
    knn_kernel<<<(B * N + 3) / 4, 256, 0, stream>>>(coords, soa, mask, cnt_all,
                                                    outd, outi, B, N);
}

// Round 4
// 61.626 us; speedup vs baseline: 1.7774x; 1.7774x over previous
//
#include <hip/hip_runtime.h>
#include <stdint.h>

#define NTYPES 12
#define EMB 128
#define KNN 30
#define SEPS_F 1e-6f
#define LEPS_F 1e6f
#define NATOMS 4800
#define ITEMS 76            // 75 real + 1 pad per lane
#define GROUPS 19           // ITEMS / 4
#define PADN 4864           // GROUPS * 256 floats per SoA array per batch
#define CAPC 192            // candidate capacity per wave
#define SENT_BITS 0x7F7FFFFFu   // FLT_MAX bits: sentinel for masked items

typedef unsigned long long ull;

__device__ __forceinline__ ull shfl_xor64(ull v, int m) {
    int lo = (int)(unsigned)(v & 0xffffffffull);
    int hi = (int)(unsigned)(v >> 32);
    lo = __shfl_xor(lo, m, 64);
    hi = __shfl_xor(hi, m, 64);
    return ((ull)(unsigned)hi << 32) | (unsigned)lo;
}

// ---------------- prep: mask counts + graph-norm affine coeffs, fused ----------------
__global__ __launch_bounds__(256) void prep_kernel(const float* __restrict__ mask,
                                                   const float* __restrict__ w,
                                                   const float* __restrict__ scale,
                                                   const float* __restrict__ shift,
                                                   float* __restrict__ cnt_all,
                                                   float* __restrict__ Aa,
                                                   float* __restrict__ Bb, int N) {
    __shared__ float lc[NTYPES];
    __shared__ float ltot;
    const int b = blockIdx.x;
    const int t = threadIdx.x;
    if (t < NTYPES) lc[t] = 0.f;
    if (t == 0) ltot = 0.f;
    __syncthreads();

    // n = t + 256*i ; n%12 = (t + 4*(i%3)) % 12  -> only 3 types per thread
    float s0 = 0.f, s1 = 0.f, s2 = 0.f, tot = 0.f;
    const float* mb = mask + (size_t)b * N;
#pragma unroll
    for (int base = 0; base < 21; base += 3) {
        int n0 = t + 256 * base;
        if (n0 < N) { float m = mb[n0]; s0 += m; tot += m; }
        int n1 = t + 256 * (base + 1);
        if (n1 < N) { float m = mb[n1]; s1 += m; tot += m; }
        int n2 = t + 256 * (base + 2);
        if (n2 < N) { float m = mb[n2]; s2 += m; tot += m; }
    }
    atomicAdd(&lc[t % NTYPES], s0);
    atomicAdd(&lc[(t + 4) % NTYPES], s1);
    atomicAdd(&lc[(t + 8) % NTYPES], s2);
    for (int s = 32; s >= 1; s >>= 1) tot += __shfl_xor(tot, s, 64);
    if ((t & 63) == 0) atomicAdd(&ltot, tot);
    __syncthreads();

    if (t < EMB) {
        const int d = t;
        float cnt = ltot;
        float c = (cnt == 0.f) ? 1.f : cnt;
        float mean = 0.f;
#pragma unroll
        for (int tt = 0; tt < NTYPES; ++tt) mean += w[tt * EMB + d] * lc[tt];
        mean /= c;
        float S = 0.f;
#pragma unroll
        for (int tt = 0; tt < NTYPES; ++tt) {
            float dv = w[tt * EMB + d] - mean;
            S += lc[tt] * dv * dv;
        }
        S += ((float)N - cnt) * mean * mean;
        float stdv = sqrtf(S / c + SEPS_F);
        float g = scale[d] / stdv;
        Aa[b * EMB + d] = g;
        Bb[b * EMB + d] = shift[d] - mean * g;
    }
    if (t == 0) cnt_all[b] = ltot;
}

// ---------------- SoA transpose: group-interleaved layout for x4 loads ----------------
// item t of lane l <-> atom j = t*64 + l ; slot = (t/4)*256 + l*4 + (t%4)
__global__ __launch_bounds__(256) void soa_kernel(const float* __restrict__ coords,
                                                  float* __restrict__ soa, int N) {
    const int b = blockIdx.y;
    const int j = blockIdx.x * 256 + threadIdx.x;   // 0..PADN-1
    float x, y, z;
    int slot;
    if (j < N) {
        int t = j >> 6, l = j & 63;
        slot = (t >> 2) * 256 + l * 4 + (t & 3);
        const float* cp = coords + ((size_t)b * N + j) * 3;
        x = cp[0]; y = cp[1]; z = cp[2];
    } else {
        int l = j - N;                              // pad item t = ITEMS-1
        slot = (GROUPS - 1) * 256 + l * 4 + 3;
        x = y = z = 1.0e30f;                        // d2 overflows to +inf
    }
    float* base = soa + (size_t)b * 3 * PADN;
    base[0 * PADN + slot] = x;
    base[1 * PADN + slot] = y;
    base[2 * PADN + slot] = z;
}

// ---------------- embedding write (float4) ----------------
__global__ __launch_bounds__(256) void emb_kernel(const float* __restrict__ w,
                                                  const float* __restrict__ mask,
                                                  const float* __restrict__ Aa,
                                                  const float* __restrict__ Bb,
                                                  float* __restrict__ out0, int N) {
    const int b = blockIdx.y;
    const int idx = blockIdx.x * 256 + threadIdx.x;   // [0, N*EMB/4)
    const int d4 = idx & 31;
    const int n = idx >> 5;
    float m = mask[b * N + n];
    const float4 wv = *(const float4*)(w + (n % NTYPES) * EMB + d4 * 4);
    const float4 av = *(const float4*)(Aa + b * EMB + d4 * 4);
    const float4 bv = *(const float4*)(Bb + b * EMB + d4 * 4);
    float4 o;
    o.x = (wv.x * m * av.x + bv.x) * m;
    o.y = (wv.y * m * av.y + bv.y) * m;
    o.z = (wv.z * m * av.z + bv.z) * m;
    o.w = (wv.w * m * av.w + bv.w) * m;
    *(float4*)(out0 + (size_t)b * N * EMB + (size_t)idx * 4) = o;
}

// ---------------- exact 30-NN: one wave per query row ----------------
__global__ __launch_bounds__(256) void knn_kernel(const float* __restrict__ coords,
                                                  const float* __restrict__ soa,
                                                  const float* __restrict__ mask,
                                                  const float* __restrict__ cnt_all,
                                                  float* __restrict__ outd,
                                                  float* __restrict__ outi,
                                                  int B, int N) {
    __shared__ ull cand[4][CAPC];
    const int wave = threadIdx.x >> 6;
    const int lane = threadIdx.x & 63;
    int row = blockIdx.x * 4 + wave;
    const int total = B * N;
    if (row >= total) row = total - 1;
    const int b = row / N;
    const int i = row - b * N;

    const float* mb = mask + (size_t)b * N;
    const float* cp = coords + ((size_t)b * N + i) * 3;
    const float qx = cp[0], qy = cp[1], qz = cp[2];
    const float mi = mb[i];

    if (mi == 0.f) {
        if (lane < KNN) {
            size_t o0 = (size_t)row * KNN + lane;
            outd[o0] = LEPS_F;
            outi[o0] = -1.f;
        }
        return;
    }

    const bool allOnes = (cnt_all[b] == (float)N);
    const float* xs = soa + (size_t)b * 3 * PADN;
    const float* ys = xs + PADN;
    const float* zs = ys + PADN;
    const int loff = lane << 2;

    unsigned bits[ITEMS];
    unsigned lm = 0xFFFFFFFFu;
    if (allOnes) {
#pragma unroll
        for (int g = 0; g < GROUPS; ++g) {
            const float4 xv = *(const float4*)(xs + g * 256 + loff);
            const float4 yv = *(const float4*)(ys + g * 256 + loff);
            const float4 zv = *(const float4*)(zs + g * 256 + loff);
#pragma unroll
            for (int r = 0; r < 4; ++r) {
                float x = (r == 0) ? xv.x : (r == 1) ? xv.y : (r == 2) ? xv.z : xv.w;
                float y = (r == 0) ? yv.x : (r == 1) ? yv.y : (r == 2) ? yv.z : yv.w;
                float z = (r == 0) ? zv.x : (r == 1) ? zv.y : (r == 2) ? zv.z : zv.w;
                float dx = __fsub_rn(x, qx), dy = __fsub_rn(y, qy), dz = __fsub_rn(z, qz);
                float d2 = __fadd_rn(__fadd_rn(__fmul_rn(dx, dx), __fmul_rn(dy, dy)),
                                     __fmul_rn(dz, dz));
                unsigned ub = __float_as_uint(d2);   // pad item -> +inf bits, never selected
                bits[4 * g + r] = ub;
                lm = (ub < lm) ? ub : lm;
            }
        }
    } else {
#pragma unroll
        for (int g = 0; g < GROUPS; ++g) {
            const float4 xv = *(const float4*)(xs + g * 256 + loff);
            const float4 yv = *(const float4*)(ys + g * 256 + loff);
            const float4 zv = *(const float4*)(zs + g * 256 + loff);
#pragma unroll
            for (int r = 0; r < 4; ++r) {
                int t = 4 * g + r;
                unsigned ub;
                if (t == ITEMS - 1) {
                    ub = 0xFFFFFFFFu;               // pad: no mask load (OOB)
                } else {
                    float x = (r == 0) ? xv.x : (r == 1) ? xv.y : (r == 2) ? xv.z : xv.w;
                    float y = (r == 0) ? yv.x : (r == 1) ? yv.y : (r == 2) ? yv.z : yv.w;
                    float z = (r == 0) ? zv.x : (r == 1) ? zv.y : (r == 2) ? zv.z : zv.w;
                    float dx = __fsub_rn(x, qx), dy = __fsub_rn(y, qy), dz = __fsub_rn(z, qz);
                    float d2 = __fadd_rn(__fadd_rn(__fmul_rn(dx, dx), __fmul_rn(dy, dy)),
                                         __fmul_rn(dz, dz));
                    ub = __float_as_uint(d2);
                    if (mb[t * 64 + lane] == 0.f) ub = SENT_BITS;
                }
                bits[t] = ub;
                lm = (ub < lm) ? ub : lm;
            }
        }
    }

    // ---- threshold estimate: ~35th smallest of the 64 lane-mins ----
    unsigned mx = lm;
    for (int s = 32; s >= 1; s >>= 1) {
        unsigned o = (unsigned)__shfl_xor((int)mx, s, 64);
        mx = (o > mx) ? o : mx;
    }
    unsigned elo = 0, ehi = mx;
    while (elo + 4096u < ehi) {
        unsigned mid = elo + ((ehi - elo) >> 1);
        int cnt = __popcll(__ballot(lm <= mid));
        if (cnt >= 35) ehi = mid; else elo = mid + 1;
    }
    unsigned T = ehi;

    // ---- fused count + compact (ascending atom index), window-adjusted ----
    ull* cw = cand[wave];
    const ull lmaskLT = (1ull << lane) - 1ull;
    int c;
    unsigned blo = 0, bhi = SENT_BITS;
    bool forced = false;
    for (;;) {
        c = 0;
#pragma unroll
        for (int k = 0; k < ITEMS; ++k) {
            bool p = (bits[k] <= T);
            ull bal = __ballot(p);
            if (p) {
                int pos = c + __popcll(bal & lmaskLT);
                if (pos < CAPC)
                    cw[pos] = ((ull)bits[k] << 32) | (unsigned)(k * 64 + lane);
            }
            c += __popcll(bal);
        }
        if (forced || (c >= KNN + 1 && c <= CAPC)) break;
        if (c < KNN + 1) blo = T + 1; else bhi = T - 1;
        if (blo > bhi) { T = blo; forced = true; }
        else T = blo + ((bhi - blo) >> 1);
    }
    if (c > CAPC) c = CAPC;

    asm volatile("s_waitcnt lgkmcnt(0)" ::: "memory");

    if (c <= 64) {
        ull key = ~0ull;
        if (lane < c) {
            ull kk = cw[lane];
            unsigned db = (unsigned)(kk >> 32);
            unsigned jj = (unsigned)kk;
            float dist;
            if (db == SENT_BITS || jj == (unsigned)i) dist = LEPS_F;
            else dist = __fsqrt_rn(__fadd_rn(__uint_as_float(db), SEPS_F));
            key = ((ull)__float_as_uint(dist) << 32) | jj;
        }
        for (int kk2 = 2; kk2 <= 64; kk2 <<= 1) {
            for (int jj2 = kk2 >> 1; jj2 > 0; jj2 >>= 1) {
                ull o = shfl_xor64(key, jj2);
                bool up = ((lane & kk2) == 0);
                bool takeMin = (((lane & jj2) == 0) == up);
                ull mn2 = (key < o) ? key : o;
                ull mx2 = (key < o) ? o : key;
                key = takeMin ? mn2 : mx2;
            }
        }
        if (lane < KNN) {
            unsigned db = (unsigned)(key >> 32);
            unsigned jj = (unsigned)key;
            float dv = __uint_as_float(db);
            float iv = (jj == (unsigned)i) ? -1.f : (float)jj;
            size_t o0 = (size_t)row * KNN + lane;
            outd[o0] = dv;
            outi[o0] = iv;
        }
    } else {
        for (int ci = lane; ci < c; ci += 64) {
            ull kk = cw[ci];
            unsigned db = (unsigned)(kk >> 32);
            unsigned jj = (unsigned)kk;
            float dist;
            if (db == SENT_BITS || jj == (unsigned)i) dist = LEPS_F;
            else dist = __fsqrt_rn(__fadd_rn(__uint_as_float(db), SEPS_F));
            cw[ci] = ((ull)__float_as_uint(dist) << 32) | jj;
        }
        asm volatile("s_waitcnt lgkmcnt(0)" ::: "memory");
        for (int ci = lane; ci < c; ci += 64) {
            ull key = cw[ci];
            int rank = 0;
            for (int o = 0; o < c; ++o) rank += (cw[o] < key) ? 1 : 0;
            if (rank < KNN) {
                unsigned db = (unsigned)(key >> 32);
                unsigned jj = (unsigned)key;
                float dv = __uint_as_float(db);
                float iv = (jj == (unsigned)i) ? -1.f : (float)jj;
                size_t o0 = (size_t)row * KNN + rank;
                outd[o0] = dv;
                outi[o0] = iv;
            }
        }
    }
}

extern "C" void kernel_launch(void* const* d_in, const int* in_sizes, int n_in,
                              void* d_out, int out_size, void* d_ws, size_t ws_size,
                              hipStream_t stream) {
    const float* coords = (const float*)d_in[0];
    const float* mask   = (const float*)d_in[1];
    const float* w      = (const float*)d_in[2];
    const float* scale  = (const float*)d_in[3];
    const float* shift  = (const float*)d_in[4];

    int BN = in_sizes[1];          // B*N
    int N  = NATOMS;
    int B  = BN / N;

    float* ws0     = (float*)d_ws;
    float* cnt_all = ws0;                     // B (padded to 16)
    float* Aa      = ws0 + 16;                // B*128
    float* Bb      = Aa + B * EMB;            // B*128
    float* soa     = Bb + B * EMB;            // B*3*PADN

    float* out0 = (float*)d_out;                      // B*N*128
    float* outd = out0 + (size_t)B * N * EMB;         // B*N*30
    float* outi = outd + (size_t)B * N * KNN;         // B*N*30 (indices as float)

    prep_kernel<<<B, 256, 0, stream>>>(mask, w, scale, shift, cnt_all, Aa, Bb, N);
    soa_kernel<<<dim3(PADN / 256, B), 256, 0, stream>>>(coords, soa, N);
    emb_kernel<<<dim3(N * EMB / 4 / 256, B), 256, 0, stream>>>(w, mask, Aa, Bb, out0, N);
    knn_kernel<<<(B * N + 3) / 4, 256, 0, stream>>>(coords, soa, mask, cnt_all,
                                                    outd, outi, B, N);
}

// Round 5
// 48.177 us; speedup vs baseline: 2.2736x; 1.2791x over previous
//
#include <hip/hip_runtime.h>
#include <stdint.h>

#define NTYPES 12
#define EMB 128
#define KNN 30
#define SEPS_F 1e-6f
#define LEPS_F 1e6f
#define NATOMS 4800
#define ITEMS 76            // 75 real + 1 pad per lane
#define PAIRS 38            // ITEMS/2 packed regs
#define GROUPS 19           // ITEMS / 4
#define PADN 4864           // GROUPS * 256 floats per SoA array per batch
#define CAPC 192            // candidate capacity per wave
#define SENT_BITS 0x7F7FFFFFu   // FLT_MAX bits: sentinel for masked items

typedef unsigned long long ull;

__device__ __forceinline__ ull shfl_xor64(ull v, int m) {
    int lo = (int)(unsigned)(v & 0xffffffffull);
    int hi = (int)(unsigned)(v >> 32);
    lo = __shfl_xor(lo, m, 64);
    hi = __shfl_xor(hi, m, 64);
    return ((ull)(unsigned)hi << 32) | (unsigned)lo;
}

// d2 with plain rn ops (no FMA contraction) — must match numpy bit-exactly
__device__ __forceinline__ unsigned d2bits(float x, float y, float z,
                                           float qx, float qy, float qz) {
    float dx = __fsub_rn(x, qx), dy = __fsub_rn(y, qy), dz = __fsub_rn(z, qz);
    float d2 = __fadd_rn(__fadd_rn(__fmul_rn(dx, dx), __fmul_rn(dy, dy)),
                         __fmul_rn(dz, dz));
    return __float_as_uint(d2);
}

// ---------------- prep (blocks 0..B-1) + SoA transpose (rest) ----------------
__global__ __launch_bounds__(256) void prep_soa_kernel(const float* __restrict__ mask,
                                                       const float* __restrict__ w,
                                                       const float* __restrict__ scale,
                                                       const float* __restrict__ shift,
                                                       const float* __restrict__ coords,
                                                       float* __restrict__ cnt_all,
                                                       float* __restrict__ Aa,
                                                       float* __restrict__ Bb,
                                                       float* __restrict__ soa,
                                                       int B, int N) {
    if ((int)blockIdx.x < B) {
        // ---- prep: mask counts + graph-norm affine coeffs ----
        __shared__ float lc[NTYPES];
        __shared__ float ltot;
        const int b = blockIdx.x;
        const int t = threadIdx.x;
        if (t < NTYPES) lc[t] = 0.f;
        if (t == 0) ltot = 0.f;
        __syncthreads();
        float s0 = 0.f, s1 = 0.f, s2 = 0.f, tot = 0.f;
        const float* mb = mask + (size_t)b * N;
#pragma unroll
        for (int base = 0; base < 21; base += 3) {
            int n0 = t + 256 * base;
            if (n0 < N) { float m = mb[n0]; s0 += m; tot += m; }
            int n1 = t + 256 * (base + 1);
            if (n1 < N) { float m = mb[n1]; s1 += m; tot += m; }
            int n2 = t + 256 * (base + 2);
            if (n2 < N) { float m = mb[n2]; s2 += m; tot += m; }
        }
        atomicAdd(&lc[t % NTYPES], s0);
        atomicAdd(&lc[(t + 4) % NTYPES], s1);
        atomicAdd(&lc[(t + 8) % NTYPES], s2);
        for (int s = 32; s >= 1; s >>= 1) tot += __shfl_xor(tot, s, 64);
        if ((t & 63) == 0) atomicAdd(&ltot, tot);
        __syncthreads();
        if (t < EMB) {
            const int d = t;
            float cnt = ltot;
            float c = (cnt == 0.f) ? 1.f : cnt;
            float mean = 0.f;
#pragma unroll
            for (int tt = 0; tt < NTYPES; ++tt) mean += w[tt * EMB + d] * lc[tt];
            mean /= c;
            float S = 0.f;
#pragma unroll
            for (int tt = 0; tt < NTYPES; ++tt) {
                float dv = w[tt * EMB + d] - mean;
                S += lc[tt] * dv * dv;
            }
            S += ((float)N - cnt) * mean * mean;
            float stdv = sqrtf(S / c + SEPS_F);
            float g = scale[d] / stdv;
            Aa[b * EMB + d] = g;
            Bb[b * EMB + d] = shift[d] - mean * g;
        }
        if (t == 0) cnt_all[b] = ltot;
    } else {
        // ---- SoA: item t of lane l <-> atom j = t*64+l ; slot=(t/4)*256+l*4+(t%4)
        int idx = blockIdx.x - B;
        const int b = idx / GROUPS;
        const int chunk = idx % GROUPS;
        const int j = chunk * 256 + threadIdx.x;   // 0..PADN-1
        float x, y, z;
        int slot;
        if (j < N) {
            int t = j >> 6, l = j & 63;
            slot = (t >> 2) * 256 + l * 4 + (t & 3);
            const float* cp = coords + ((size_t)b * N + j) * 3;
            x = cp[0]; y = cp[1]; z = cp[2];
        } else {
            int l = j - N;                          // pad item t = ITEMS-1
            slot = (GROUPS - 1) * 256 + l * 4 + 3;
            x = y = z = 1.0e30f;                    // d2 overflows to +inf
        }
        float* base = soa + (size_t)b * 3 * PADN;
        base[0 * PADN + slot] = x;
        base[1 * PADN + slot] = y;
        base[2 * PADN + slot] = z;
    }
}

// ---------------- exact 30-NN (one wave/row) + fused embedding write ----------------
__global__ __launch_bounds__(256) void knn_kernel(const float* __restrict__ coords,
                                                  const float* __restrict__ soa,
                                                  const float* __restrict__ mask,
                                                  const float* __restrict__ cnt_all,
                                                  const float* __restrict__ w,
                                                  const float* __restrict__ Aa,
                                                  const float* __restrict__ Bb,
                                                  float* __restrict__ out0,
                                                  float* __restrict__ outd,
                                                  float* __restrict__ outi,
                                                  int B, int N) {
    __shared__ unsigned candj[4][CAPC];
    __shared__ ull candk[4][CAPC];
    const int wave = threadIdx.x >> 6;
    const int lane = threadIdx.x & 63;
    int row = blockIdx.x * 4 + wave;
    const int total = B * N;
    if (row >= total) row = total - 1;
    const int b = row / N;
    const int i = row - b * N;

    const float* mb = mask + (size_t)b * N;
    const float mi = mb[i];

    // ---- fused embedding write for this row (128 floats, float2/lane) ----
    {
        const int d0 = lane * 2;
        const float2 wv = *(const float2*)(w + (i % NTYPES) * EMB + d0);
        const float2 av = *(const float2*)(Aa + b * EMB + d0);
        const float2 bv = *(const float2*)(Bb + b * EMB + d0);
        float2 o;
        o.x = (wv.x * mi * av.x + bv.x) * mi;
        o.y = (wv.y * mi * av.y + bv.y) * mi;
        *(float2*)(out0 + ((size_t)b * N + i) * EMB + d0) = o;
    }

    if (mi == 0.f) {
        if (lane < KNN) {
            size_t o0 = (size_t)row * KNN + lane;
            outd[o0] = LEPS_F;
            outi[o0] = -1.f;
        }
        return;
    }

    const float* cp = coords + ((size_t)b * N + i) * 3;
    const float qx = cp[0], qy = cp[1], qz = cp[2];
    const bool allOnes = (cnt_all[b] == (float)N);
    const float* xs = soa + (size_t)b * 3 * PADN;
    const float* ys = xs + PADN;
    const float* zs = ys + PADN;
    const int loff = lane << 2;

    // ---- packed 16-bit d2 pass: 2 items per VGPR ----
    unsigned pk[PAIRS];
    unsigned lm = 0xFFFFFFFFu;
    if (allOnes) {
#pragma unroll
        for (int g = 0; g < GROUPS; ++g) {
            const float4 xv = *(const float4*)(xs + g * 256 + loff);
            const float4 yv = *(const float4*)(ys + g * 256 + loff);
            const float4 zv = *(const float4*)(zs + g * 256 + loff);
            unsigned u0 = d2bits(xv.x, yv.x, zv.x, qx, qy, qz);
            unsigned u1 = d2bits(xv.y, yv.y, zv.y, qx, qy, qz);
            unsigned u2 = d2bits(xv.z, yv.z, zv.z, qx, qy, qz);
            unsigned u3 = d2bits(xv.w, yv.w, zv.w, qx, qy, qz);
            unsigned m01 = (u0 < u1) ? u0 : u1;
            unsigned m23 = (u2 < u3) ? u2 : u3;
            unsigned m03 = (m01 < m23) ? m01 : m23;
            lm = (m03 < lm) ? m03 : lm;
            pk[2 * g]     = __builtin_amdgcn_perm(u1, u0, 0x07060302u);
            pk[2 * g + 1] = __builtin_amdgcn_perm(u3, u2, 0x07060302u);
        }
    } else {
#pragma unroll
        for (int g = 0; g < GROUPS; ++g) {
            const float4 xv = *(const float4*)(xs + g * 256 + loff);
            const float4 yv = *(const float4*)(ys + g * 256 + loff);
            const float4 zv = *(const float4*)(zs + g * 256 + loff);
            unsigned u0 = d2bits(xv.x, yv.x, zv.x, qx, qy, qz);
            unsigned u1 = d2bits(xv.y, yv.y, zv.y, qx, qy, qz);
            unsigned u2 = d2bits(xv.z, yv.z, zv.z, qx, qy, qz);
            unsigned u3 = d2bits(xv.w, yv.w, zv.w, qx, qy, qz);
            if (mb[(4 * g + 0) * 64 + lane] == 0.f) u0 = SENT_BITS;
            if (mb[(4 * g + 1) * 64 + lane] == 0.f) u1 = SENT_BITS;
            if (mb[(4 * g + 2) * 64 + lane] == 0.f) u2 = SENT_BITS;
            if (g == GROUPS - 1) u3 = 0xFFFFFFFFu;   // pad item: no mask load (OOB)
            else if (mb[(4 * g + 3) * 64 + lane] == 0.f) u3 = SENT_BITS;
            unsigned m01 = (u0 < u1) ? u0 : u1;
            unsigned m23 = (u2 < u3) ? u2 : u3;
            unsigned m03 = (m01 < m23) ? m01 : m23;
            lm = (m03 < lm) ? m03 : lm;
            pk[2 * g]     = __builtin_amdgcn_perm(u1, u0, 0x07060302u);
            pk[2 * g + 1] = __builtin_amdgcn_perm(u3, u2, 0x07060302u);
        }
    }

    // ---- threshold: ~35th smallest of 64 lane-mins, bisected in 16-bit space ----
    unsigned lm16 = lm >> 16;
    unsigned mx = lm16;
    for (int s = 32; s >= 1; s >>= 1) {
        unsigned o = (unsigned)__shfl_xor((int)mx, s, 64);
        mx = (o > mx) ? o : mx;
    }
    unsigned elo = 0, ehi = mx;
    while (elo < ehi) {
        unsigned mid = (elo + ehi) >> 1;
        int cnt = __popcll(__ballot(lm16 <= mid));
        if (cnt >= 35) ehi = mid; else elo = mid + 1;
    }
    unsigned T16 = ehi;      // first-pass count guaranteed >= 35

    // ---- fused count + compact (indices only), window-adjusted ----
    unsigned* cwi = candj[wave];
    const ull lmaskLT = (1ull << lane) - 1ull;
    int c;
    unsigned blo = 0, bhi = 0xFFFFu;
    bool forced = false;
    for (;;) {
        c = 0;
#pragma unroll
        for (int p = 0; p < PAIRS; ++p) {
            unsigned reg = pk[p];
            bool pe = (reg & 0xFFFFu) <= T16;
            ull be = __ballot(pe);
            if (pe) {
                int pos = c + __popcll(be & lmaskLT);
                if (pos < CAPC) cwi[pos] = (unsigned)((2 * p) * 64 + lane);
            }
            c += __popcll(be);
            bool po = (reg >> 16) <= T16;
            ull bo = __ballot(po);
            if (po) {
                int pos = c + __popcll(bo & lmaskLT);
                if (pos < CAPC) cwi[pos] = (unsigned)((2 * p + 1) * 64 + lane);
            }
            c += __popcll(bo);
        }
        if (forced || (c >= KNN + 1 && c <= CAPC)) break;
        if (c < KNN + 1) blo = T16 + 1; else bhi = T16 - 1;
        if (blo > bhi) { T16 = blo; forced = true; }
        else T16 = blo + ((bhi - blo) >> 1);
    }
    if (c > CAPC) c = CAPC;

    asm volatile("s_waitcnt lgkmcnt(0)" ::: "memory");

    if (c <= 64) {
        // ---- recompute exact keys for candidates, register bitonic sort ----
        ull key = ~0ull;
        if (lane < c) {
            int j = (int)cwi[lane];
            if (j < N) {
                const float* cj = coords + ((size_t)b * N + j) * 3;
                float mj = mb[j];
                unsigned db = d2bits(cj[0], cj[1], cj[2], qx, qy, qz);
                float dist;
                if (j == i || mj == 0.f) dist = LEPS_F;
                else dist = __fsqrt_rn(__fadd_rn(__uint_as_float(db), SEPS_F));
                key = ((ull)__float_as_uint(dist) << 32) | (unsigned)j;
            }
        }
        for (int kk2 = 2; kk2 <= 64; kk2 <<= 1) {
            for (int jj2 = kk2 >> 1; jj2 > 0; jj2 >>= 1) {
                ull o = shfl_xor64(key, jj2);
                bool up = ((lane & kk2) == 0);
                bool takeMin = (((lane & jj2) == 0) == up);
                ull mn2 = (key < o) ? key : o;
                ull mx2 = (key < o) ? o : key;
                key = takeMin ? mn2 : mx2;
            }
        }
        if (lane < KNN) {
            unsigned db = (unsigned)(key >> 32);
            unsigned jj = (unsigned)key;
            float dv = __uint_as_float(db);
            float iv = (jj == (unsigned)i) ? -1.f : (float)jj;
            size_t o0 = (size_t)row * KNN + lane;
            outd[o0] = dv;
            outi[o0] = iv;
        }
    } else {
        // ---- rare path (64 < c <= 192): keys via LDS, all-pairs rank ----
        ull* ck = candk[wave];
        for (int ci = lane; ci < c; ci += 64) {
            int j = (int)cwi[ci];
            ull key = ~0ull;
            if (j < N) {
                const float* cj = coords + ((size_t)b * N + j) * 3;
                float mj = mb[j];
                unsigned db = d2bits(cj[0], cj[1], cj[2], qx, qy, qz);
                float dist;
                if (j == i || mj == 0.f) dist = LEPS_F;
                else dist = __fsqrt_rn(__fadd_rn(__uint_as_float(db), SEPS_F));
                key = ((ull)__float_as_uint(dist) << 32) | (unsigned)j;
            }
            ck[ci] = key;
        }
        asm volatile("s_waitcnt lgkmcnt(0)" ::: "memory");
        for (int ci = lane; ci < c; ci += 64) {
            ull key = ck[ci];
            int rank = 0;
            for (int o = 0; o < c; ++o) rank += (ck[o] < key) ? 1 : 0;
            if (rank < KNN) {
                unsigned db = (unsigned)(key >> 32);
                unsigned jj = (unsigned)key;
                float dv = __uint_as_float(db);
                float iv = (jj == (unsigned)i) ? -1.f : (float)jj;
                size_t o0 = (size_t)row * KNN + rank;
                outd[o0] = dv;
                outi[o0] = iv;
            }
        }
    }
}

extern "C" void kernel_launch(void* const* d_in, const int* in_sizes, int n_in,
                              void* d_out, int out_size, void* d_ws, size_t ws_size,
                              hipStream_t stream) {
    const float* coords = (const float*)d_in[0];
    const float* mask   = (const float*)d_in[1];
    const float* w      = (const float*)d_in[2];
    const float* scale  = (const float*)d_in[3];
    const float* shift  = (const float*)d_in[4];

    int BN = in_sizes[1];          // B*N
    int N  = NATOMS;
    int B  = BN / N;

    float* ws0     = (float*)d_ws;
    float* cnt_all = ws0;                     // B (padded to 16)
    float* Aa      = ws0 + 16;                // B*128
    float* Bb      = Aa + B * EMB;            // B*128
    float* soa     = Bb + B * EMB;            // B*3*PADN

    float* out0 = (float*)d_out;                      // B*N*128
    float* outd = out0 + (size_t)B * N * EMB;         // B*N*30
    float* outi = outd + (size_t)B * N * KNN;         // B*N*30 (indices as float)

    prep_soa_kernel<<<B + B * GROUPS, 256, 0, stream>>>(mask, w, scale, shift, coords,
                                                        cnt_all, Aa, Bb, soa, B, N);
    knn_kernel<<<(B * N + 3) / 4, 256, 0, stream>>>(coords, soa, mask, cnt_all,
                                                    w, Aa, Bb, out0, outd, outi, B, N);
}

// Round 6
// 47.443 us; speedup vs baseline: 2.3088x; 1.0155x over previous
//
#include <hip/hip_runtime.h>
#include <stdint.h>

#define NTYPES 12
#define EMB 128
#define KNN 30
#define SEPS_F 1e-6f
#define LEPS_F 1e6f
#define NATOMS 4800
#define GROUPS 19           // 4-item groups per row (76 items incl 1 stored pad)
#define G0 10               // groups owned by half 0 (half 1 owns 9 + 1 virtual pad pair)
#define NPAIR 20            // packed u16-pair regs per half (uniform)
#define PADN 4864           // GROUPS * 256 floats per SoA array per batch
#define CAPH 128            // per-half candidate cap
#define CAPT 256            // total candidate capacity
#define SENT_BITS 0x7F7FFFFFu   // FLT_MAX bits: sentinel for masked items

typedef unsigned long long ull;

// filter d2: FMA allowed (superset selection with bucket margin)
__device__ __forceinline__ unsigned d2f(float x, float y, float z,
                                        float qx, float qy, float qz) {
    float dx = __fsub_rn(x, qx), dy = __fsub_rn(y, qy), dz = __fsub_rn(z, qz);
    float d2 = __builtin_fmaf(dx, dx, __builtin_fmaf(dy, dy, __fmul_rn(dz, dz)));
    return __float_as_uint(d2);
}

// exact d2: plain rn ops, must match numpy bit-for-bit
__device__ __forceinline__ unsigned d2x(float x, float y, float z,
                                        float qx, float qy, float qz) {
    float dx = __fsub_rn(x, qx), dy = __fsub_rn(y, qy), dz = __fsub_rn(z, qz);
    float d2 = __fadd_rn(__fadd_rn(__fmul_rn(dx, dx), __fmul_rn(dy, dy)),
                         __fmul_rn(dz, dz));
    return __float_as_uint(d2);
}

// ---------------- prep (blocks 0..B-1) + SoA transpose (rest) ----------------
__global__ __launch_bounds__(256) void prep_soa_kernel(const float* __restrict__ mask,
                                                       const float* __restrict__ w,
                                                       const float* __restrict__ scale,
                                                       const float* __restrict__ shift,
                                                       const float* __restrict__ coords,
                                                       float* __restrict__ cnt_all,
                                                       float* __restrict__ Aa,
                                                       float* __restrict__ Bb,
                                                       float* __restrict__ soa,
                                                       int B, int N) {
    if ((int)blockIdx.x < B) {
        __shared__ float lc[NTYPES];
        __shared__ float ltot;
        const int b = blockIdx.x;
        const int t = threadIdx.x;
        if (t < NTYPES) lc[t] = 0.f;
        if (t == 0) ltot = 0.f;
        __syncthreads();
        float s0 = 0.f, s1 = 0.f, s2 = 0.f, tot = 0.f;
        const float* mb = mask + (size_t)b * N;
#pragma unroll
        for (int base = 0; base < 21; base += 3) {
            int n0 = t + 256 * base;
            if (n0 < N) { float m = mb[n0]; s0 += m; tot += m; }
            int n1 = t + 256 * (base + 1);
            if (n1 < N) { float m = mb[n1]; s1 += m; tot += m; }
            int n2 = t + 256 * (base + 2);
            if (n2 < N) { float m = mb[n2]; s2 += m; tot += m; }
        }
        atomicAdd(&lc[t % NTYPES], s0);
        atomicAdd(&lc[(t + 4) % NTYPES], s1);
        atomicAdd(&lc[(t + 8) % NTYPES], s2);
        for (int s = 32; s >= 1; s >>= 1) tot += __shfl_xor(tot, s, 64);
        if ((t & 63) == 0) atomicAdd(&ltot, tot);
        __syncthreads();
        if (t < EMB) {
            const int d = t;
            float cnt = ltot;
            float c = (cnt == 0.f) ? 1.f : cnt;
            float mean = 0.f;
#pragma unroll
            for (int tt = 0; tt < NTYPES; ++tt) mean += w[tt * EMB + d] * lc[tt];
            mean /= c;
            float S = 0.f;
#pragma unroll
            for (int tt = 0; tt < NTYPES; ++tt) {
                float dv = w[tt * EMB + d] - mean;
                S += lc[tt] * dv * dv;
            }
            S += ((float)N - cnt) * mean * mean;
            float stdv = sqrtf(S / c + SEPS_F);
            float g = scale[d] / stdv;
            Aa[b * EMB + d] = g;
            Bb[b * EMB + d] = shift[d] - mean * g;
        }
        if (t == 0) cnt_all[b] = ltot;
    } else {
        int idx = blockIdx.x - B;
        const int b = idx / GROUPS;
        const int chunk = idx % GROUPS;
        const int j = chunk * 256 + threadIdx.x;   // 0..PADN-1
        float x, y, z;
        int slot;
        if (j < N) {
            int t = j >> 6, l = j & 63;
            slot = (t >> 2) * 256 + l * 4 + (t & 3);
            const float* cp = coords + ((size_t)b * N + j) * 3;
            x = cp[0]; y = cp[1]; z = cp[2];
        } else {
            int l = j - N;                          // stored pad item t = 75
            slot = (GROUPS - 1) * 256 + l * 4 + 3;
            x = y = z = 1.0e30f;                    // d2 -> +inf
        }
        float* base = soa + (size_t)b * 3 * PADN;
        base[0 * PADN + slot] = x;
        base[1 * PADN + slot] = y;
        base[2 * PADN + slot] = z;
    }
}

// ---------------- exact 30-NN: TWO waves per query row + fused emb ----------------
__global__ __launch_bounds__(256) void knn_kernel(const float* __restrict__ coords,
                                                  const float* __restrict__ soa,
                                                  const float* __restrict__ mask,
                                                  const float* __restrict__ cnt_all,
                                                  const float* __restrict__ w,
                                                  const float* __restrict__ Aa,
                                                  const float* __restrict__ Bb,
                                                  float* __restrict__ out0,
                                                  float* __restrict__ outd,
                                                  float* __restrict__ outi,
                                                  int B, int N) {
    __shared__ unsigned short lmx[2][2][64];   // [row][half][lane] lane-min >> 16
    __shared__ unsigned candj[2][2][CAPH];     // [row][half][slot] atom index
    __shared__ int cnts[2][2];                 // [row][half]
    __shared__ ull ck[2][CAPT];                // [row] exact keys, concatenated

    const int wv = threadIdx.x >> 6;
    const int lane = threadIdx.x & 63;
    const int rw = wv >> 1;                    // row within block
    const int hf = wv & 1;                     // half of items
    int row = blockIdx.x * 2 + rw;
    const int total = B * N;
    if (row >= total) row = total - 1;         // duplicate work, same writes
    const int b = row / N;
    const int i = row - b * N;

    const float* mb = mask + (size_t)b * N;
    const float mi = mb[i];

    // ---- fused embedding write (half 0 only; 128 floats, float2/lane) ----
    if (hf == 0) {
        const int d0 = lane * 2;
        const float2 wvv = *(const float2*)(w + (i % NTYPES) * EMB + d0);
        const float2 av = *(const float2*)(Aa + b * EMB + d0);
        const float2 bv = *(const float2*)(Bb + b * EMB + d0);
        float2 o;
        o.x = (wvv.x * mi * av.x + bv.x) * mi;
        o.y = (wvv.y * mi * av.y + bv.y) * mi;
        *(float2*)(out0 + ((size_t)b * N + i) * EMB + d0) = o;
    }

    const float* cp = coords + ((size_t)b * N + i) * 3;
    const float qx = cp[0], qy = cp[1], qz = cp[2];
    const bool allOnes = (cnt_all[b] == (float)N);
    const float* xs = soa + (size_t)b * 3 * PADN;
    const float* ys = xs + PADN;
    const float* zs = ys + PADN;
    const int loff = lane << 2;
    const int gbeg = hf ? G0 : 0;
    const int gcnt = hf ? (GROUPS - G0) : G0;  // 9 or 10

    // ---- filter pass over own half: packed 16-bit FMA-d2, track lane-min ----
    unsigned pk[NPAIR];
    unsigned lm = 0xFFFFFFFFu;
#pragma unroll
    for (int p = 0; p < G0; ++p) {
        if (p < gcnt) {
            const int g = gbeg + p;
            const float4 xv = *(const float4*)(xs + g * 256 + loff);
            const float4 yv = *(const float4*)(ys + g * 256 + loff);
            const float4 zv = *(const float4*)(zs + g * 256 + loff);
            unsigned u0 = d2f(xv.x, yv.x, zv.x, qx, qy, qz);
            unsigned u1 = d2f(xv.y, yv.y, zv.y, qx, qy, qz);
            unsigned u2 = d2f(xv.z, yv.z, zv.z, qx, qy, qz);
            unsigned u3 = d2f(xv.w, yv.w, zv.w, qx, qy, qz);
            if (!allOnes) {
                const int t = g * 4;
                if (mb[(t + 0) * 64 + lane] == 0.f) u0 = SENT_BITS;
                if (mb[(t + 1) * 64 + lane] == 0.f) u1 = SENT_BITS;
                if (mb[(t + 2) * 64 + lane] == 0.f) u2 = SENT_BITS;
                if (t + 3 < 75) {                       // t=75 is the stored pad
                    if (mb[(t + 3) * 64 + lane] == 0.f) u3 = SENT_BITS;
                }
            }
            unsigned m01 = (u0 < u1) ? u0 : u1;
            unsigned m23 = (u2 < u3) ? u2 : u3;
            unsigned m03 = (m01 < m23) ? m01 : m23;
            lm = (m03 < lm) ? m03 : lm;
            pk[2 * p]     = __builtin_amdgcn_perm(u1, u0, 0x07060302u);
            pk[2 * p + 1] = __builtin_amdgcn_perm(u3, u2, 0x07060302u);
        } else {
            pk[2 * p] = 0xFFFFFFFFu;                    // virtual pad pair (half 1)
            pk[2 * p + 1] = 0xFFFFFFFFu;
        }
    }

    // ---- exchange lane-mins, certify threshold from 128 mins ----
    unsigned lm16 = lm >> 16;
    lmx[rw][hf][lane] = (unsigned short)lm16;
    __syncthreads();
    unsigned pt16 = lmx[rw][hf ^ 1][lane];

    unsigned lo = 0, hi = 0x7F7Fu;
    while (lo < hi) {
        unsigned mid = (lo + hi) >> 1;
        int cnt = __popcll(__ballot(lm16 <= mid)) + __popcll(__ballot(pt16 <= mid));
        if (cnt >= 35) hi = mid; else lo = mid + 1;
    }
    const unsigned Tsel = lo + 1;   // +1 bucket: FMA-safety margin; count >= 35 certified

    // ---- single compact pass (no retries), per-half, ascending item order ----
    unsigned* cw = candj[rw][hf];
    const ull lmaskLT = (1ull << lane) - 1ull;
    const int ibase = hf * (4 * G0);
    int c = 0;
#pragma unroll
    for (int p = 0; p < NPAIR; ++p) {
        unsigned reg = pk[p];
        bool pe = (reg & 0xFFFFu) <= Tsel;
        ull be = __ballot(pe);
        if (pe) {
            int pos = c + __popcll(be & lmaskLT);
            if (pos < CAPH) cw[pos] = (unsigned)((ibase + 2 * p) * 64 + lane);
        }
        c += __popcll(be);
        bool po = (reg >> 16) <= Tsel;
        ull bo = __ballot(po);
        if (po) {
            int pos = c + __popcll(bo & lmaskLT);
            if (pos < CAPH) cw[pos] = (unsigned)((ibase + 2 * p + 1) * 64 + lane);
        }
        c += __popcll(bo);
    }
    if (c > CAPH) c = CAPH;
    if (lane == 0) cnts[rw][hf] = c;
    __syncthreads();
    const int c0 = cnts[rw][0];
    const int ct = c0 + cnts[rw][1];

    // ---- exact keys (reference rounding) into concatenated LDS buffer ----
    ull* ckr = ck[rw];
    const int obase = hf ? c0 : 0;
    for (int k = lane; k < c; k += 64) {
        unsigned j = cw[k];
        ull key = ~0ull;
        if (j < (unsigned)N) {
            const float* cj = coords + ((size_t)b * N + j) * 3;
            float mj = allOnes ? 1.f : mb[j];
            unsigned db = d2x(cj[0], cj[1], cj[2], qx, qy, qz);
            float dist = (j == (unsigned)i || mj == 0.f)
                             ? LEPS_F
                             : __fsqrt_rn(__fadd_rn(__uint_as_float(db), SEPS_F));
            key = ((ull)__float_as_uint(dist) << 32) | j;
        }
        ckr[obase + k] = key;
    }
    __syncthreads();

    // ---- all-pairs rank (broadcast LDS reads), waves interleave candidates ----
    for (int ci = 2 * lane + hf; ci < ct; ci += 128) {
        ull key = ckr[ci];
        int rank = 0;
        int o = 0;
        for (; o + 4 <= ct; o += 4) {
            rank += (ckr[o] < key) ? 1 : 0;
            rank += (ckr[o + 1] < key) ? 1 : 0;
            rank += (ckr[o + 2] < key) ? 1 : 0;
            rank += (ckr[o + 3] < key) ? 1 : 0;
        }
        for (; o < ct; ++o) rank += (ckr[o] < key) ? 1 : 0;
        if (rank < KNN && mi != 0.f) {
            unsigned db = (unsigned)(key >> 32);
            unsigned jj = (unsigned)key;
            size_t o0 = (size_t)row * KNN + rank;
            outd[o0] = __uint_as_float(db);
            outi[o0] = (jj == (unsigned)i) ? -1.f : (float)jj;
        }
    }

    // ---- masked query row: forced outputs ----
    if (mi == 0.f && hf == 0 && lane < KNN) {
        size_t o0 = (size_t)row * KNN + lane;
        outd[o0] = LEPS_F;
        outi[o0] = -1.f;
    }
}

extern "C" void kernel_launch(void* const* d_in, const int* in_sizes, int n_in,
                              void* d_out, int out_size, void* d_ws, size_t ws_size,
                              hipStream_t stream) {
    const float* coords = (const float*)d_in[0];
    const float* mask   = (const float*)d_in[1];
    const float* w      = (const float*)d_in[2];
    const float* scale  = (const float*)d_in[3];
    const float* shift  = (const float*)d_in[4];

    int BN = in_sizes[1];          // B*N
    int N  = NATOMS;
    int B  = BN / N;

    float* ws0     = (float*)d_ws;
    float* cnt_all = ws0;                     // B (padded to 16)
    float* Aa      = ws0 + 16;                // B*128
    float* Bb      = Aa + B * EMB;            // B*128
    float* soa     = Bb + B * EMB;            // B*3*PADN

    float* out0 = (float*)d_out;                      // B*N*128
    float* outd = out0 + (size_t)B * N * EMB;         // B*N*30
    float* outi = outd + (size_t)B * N * KNN;         // B*N*30 (indices as float)

    prep_soa_kernel<<<B + B * GROUPS, 256, 0, stream>>>(mask, w, scale, shift, coords,
                                                        cnt_all, Aa, Bb, soa, B, N);
    knn_kernel<<<(B * N + 1) / 2, 256, 0, stream>>>(coords, soa, mask, cnt_all,
                                                    w, Aa, Bb, out0, outd, outi, B, N);
}